// Round 1
// baseline (210.790 us; speedup 1.0000x reference)
//
#include <hip/hip_runtime.h>

typedef unsigned short u16;
typedef __bf16 bf16x8 __attribute__((ext_vector_type(8)));
typedef float f32x4 __attribute__((ext_vector_type(4)));

#define HH  56
#define WW  56
#define HW  3136      // 56*56
#define CC  256
#define NB  8
#define CKP 2048      // c*7 padded to c*8: channel j's taps = cols j*8..j*8+7
#define KS1 4         // split-K factor GEMM1 (49 iters -> 12/12/12/13)

// round-to-nearest-even fp32 -> bf16 (bit pattern) — for non-hot paths
__device__ __forceinline__ u16 f2bf(float f) {
  unsigned int u = __float_as_uint(f);
  u += 0x7fffu + ((u >> 16) & 1u);
  return (u16)(u >> 16);
}
__device__ __forceinline__ float bf2f(u16 v) {
  return __uint_as_float((unsigned)v << 16);
}

// async global->LDS DMA, 16B per lane; dest = wave-uniform base + lane*16
__device__ __forceinline__ void lds_load16(const void* g, void* l) {
  __builtin_amdgcn_global_load_lds(
      (const __attribute__((address_space(1))) void*)g,
      (__attribute__((address_space(3))) void*)l, 16, 0, 0);
}

// ---------------------------------------------------------------------------
// pass1: t1b = bf16(p1w * x), xb = bf16(x).  Fully coalesced float4 reads.
// grid = N*C*HW/4/256 = 6272
// ---------------------------------------------------------------------------
__global__ void pass1(const float* __restrict__ x, const float* __restrict__ p1w,
                      u16* __restrict__ t1b, u16* __restrict__ xb) {
  int i = blockIdx.x * 256 + threadIdx.x;        // over N*C*HW/4
  int cw = i % (CC * HW / 4);                    // p1w broadcast over n
  float4 xv = ((const float4*)x)[i];
  float4 wv = ((const float4*)p1w)[cw];
  uint2 xo = make_uint2((unsigned)f2bf(xv.x) | ((unsigned)f2bf(xv.y) << 16),
                        (unsigned)f2bf(xv.z) | ((unsigned)f2bf(xv.w) << 16));
  ((uint2*)xb)[i] = xo;
  uint2 to = make_uint2((unsigned)f2bf(xv.x * wv.x) | ((unsigned)f2bf(xv.y * wv.y) << 16),
                        (unsigned)f2bf(xv.z * wv.z) | ((unsigned)f2bf(xv.w * wv.w) << 16));
  ((uint2*)t1b)[i] = to;
}

// ---------------------------------------------------------------------------
// gemm1f: fused NT GEMM (split-K), 128x128 tile, BK=64.
// NEW (R9): B-gen is SELECT-ONLY bf16 — no float math.
//   B rows j*8+k (k<7) = masked taps of t2[j] (raw bf16 t1b values of ch j-1)
//   B row  j*8+7       = t1[j] row  -> output col j*8+7 = G[i][j] = <xb_i, t1_j>
// reduce1 later forms t7 = (G - H_k)/56 in fp32 (more accurate than old
// bf16(t1 - tap) rounding).  Writes fp32 partials Cp[ks][nb][256][CKP].
// grid = (2, 16, NB*KS1)
// ---------------------------------------------------------------------------
__global__ __launch_bounds__(256)
void gemm1f(const u16* __restrict__ A, const u16* __restrict__ t1b,
            float* __restrict__ Cp) {
  __shared__ u16 As[128 * 64];
  __shared__ u16 Bs[128 * 64];

  const int z = blockIdx.z, nb = z / KS1, ks = z % KS1;
  const int it0 = 49 * ks / KS1, it1 = 49 * (ks + 1) / KS1;
  const u16* Ab  = A   + (long)nb * CC * HW;
  const u16* t1n = t1b + (long)nb * CC * HW;
  const int m0 = blockIdx.x * 128, n0 = blockIdx.y * 128;
  const int jb = blockIdx.y * 16;                 // first channel of tile
  const int t = threadIdx.x;
  const int lane = t & 63, wave = t >> 6;
  const int wm = wave & 1, wn = wave >> 1;        // 2x2 waves, 64x64 each
  const int lm = lane & 15, quad = lane >> 4;

  // B-gen mapping
  const int jl = (t >> 3) & 15, pc = t & 7, hf = t >> 7;
  const int j  = jb + jl;
  const int jm = (j + CC - 1) & (CC - 1);
  const u16* arow = t1n + (long)j  * HW;
  const u16* wrow = t1n + (long)jm * HW;

  f32x4 acc[4][4];
#pragma unroll
  for (int a = 0; a < 4; ++a)
#pragma unroll
    for (int b = 0; b < 4; ++b) acc[a][b] = (f32x4)0.0f;

  // A staging geometry: 1024 chunks of 16B, 4 per thread, XOR swizzle
  int rowc[4], colc[4];
#pragma unroll
  for (int ci = 0; ci < 4; ++ci) {
    int c = t + ci * 256;
    rowc[ci] = c >> 3;
    colc[ci] = ((c & 7) ^ (rowc[ci] & 7)) * 8;
  }

  for (int it = it0; it < it1; ++it) {
    const int k0 = it * 64;
#pragma unroll
    for (int ci = 0; ci < 4; ++ci)
      lds_load16(Ab + (long)(m0 + rowc[ci]) * HW + k0 + colc[ci],
                 &As[(t + ci * 256) * 8]);

    // ---- B-gen: 8 p-values (p8..p8+7), rows jl*8+k. Pure u16 selects. ----
    {
      const int p8 = k0 + pc * 8;
      __attribute__((aligned(16))) u16 Ar[8];
      __attribute__((aligned(16))) u16 Wd[24];     // window = flat [p8-8, p8+16)
      *(uint4*)Ar = *(const uint4*)&arow[p8];
#pragma unroll
      for (int L = 0; L < 3; ++L) {
        int ad = p8 - 8 + L * 8;
        ad = ad < 0 ? 0 : (ad > HW - 8 ? HW - 8 : ad);  // garbage only at masked idx
        *(uint4*)&Wd[L * 8] = *(const uint4*)&wrow[ad];
      }
      const int w0t = p8 % 56;
      int wv[8];
#pragma unroll
      for (int e = 0; e < 8; ++e) { int w = w0t + e; wv[e] = w >= 56 ? w - 56 : w; }
      if (hf == 0) {                           // k = 0..3
#pragma unroll
        for (int k = 0; k < 4; ++k) {
          __attribute__((aligned(16))) u16 v[8];
#pragma unroll
          for (int e = 0; e < 8; ++e)
            v[e] = ((unsigned)(wv[e] + k - 3) < 56u) ? Wd[e + k + 5] : (u16)0;
          *(uint4*)&Bs[(jl * 8 + k) * 64 + (pc ^ k) * 8] = *(const uint4*)v;
        }
      } else {                                 // k = 4..6 + G-row (slot 7)
#pragma unroll
        for (int k = 4; k < 7; ++k) {
          __attribute__((aligned(16))) u16 v[8];
#pragma unroll
          for (int e = 0; e < 8; ++e)
            v[e] = ((unsigned)(wv[e] + k - 3) < 56u) ? Wd[e + k + 5] : (u16)0;
          *(uint4*)&Bs[(jl * 8 + k) * 64 + (pc ^ k) * 8] = *(const uint4*)v;
        }
        // slot 7 = t1[j] row -> produces G[i][j] in output col j*8+7
        *(uint4*)&Bs[(jl * 8 + 7) * 64 + (pc ^ 7) * 8] = *(const uint4*)Ar;
      }
    }
    __syncthreads();
#pragma unroll
    for (int kk = 0; kk < 2; ++kk) {
      const int phys = ((kk * 4 + quad) ^ (lm & 7)) * 8;
      bf16x8 af[4], bv[4];
#pragma unroll
      for (int mi = 0; mi < 4; ++mi)
        af[mi] = *(const bf16x8*)&As[(wm * 64 + mi * 16 + lm) * 64 + phys];
#pragma unroll
      for (int ni = 0; ni < 4; ++ni)
        bv[ni] = *(const bf16x8*)&Bs[(wn * 64 + ni * 16 + lm) * 64 + phys];
#pragma unroll
      for (int mi = 0; mi < 4; ++mi)
#pragma unroll
        for (int ni = 0; ni < 4; ++ni)
          acc[mi][ni] = __builtin_amdgcn_mfma_f32_16x16x32_bf16(
              af[mi], bv[ni], acc[mi][ni], 0, 0, 0);
    }
    __syncthreads();
  }

  // fp32 partial store; C/D layout: col = lane&15, row = quad*4 + reg
  float* Cb = Cp + ((long)ks * NB + nb) * (long)CC * CKP;
#pragma unroll
  for (int mi = 0; mi < 4; ++mi)
#pragma unroll
    for (int ni = 0; ni < 4; ++ni) {
      int rb = m0 + wm * 64 + mi * 16 + quad * 4;
      int cg = n0 + wn * 64 + ni * 16 + lm;
#pragma unroll
      for (int r = 0; r < 4; ++r)
        Cb[(long)(rb + r) * CKP + cg] = acc[mi][ni][r];
    }
}

// ---------------------------------------------------------------------------
// reduce1 (R9): per thread = one j-group (8 cols).  Sums KS1 partials,
// forms t7[jk] = (G - H_k)/56 for k<7 (fp32 subtract), and writes
// S7 = sum_k t7[jk] into slot 7 (consumed by gemm2f's pad MFMA slots).
// grid = NB*CC*CKP/8/256 = 2048
// ---------------------------------------------------------------------------
__global__ void reduce1(const float* __restrict__ p1, u16* __restrict__ t7) {
  const int g = blockIdx.x * 256 + threadIdx.x;   // j-group over NB*CC*CKP/8
  const long S = (long)NB * CC * CKP;             // elements per partial
  const long base = (long)g * 8;
  float a[8];
#pragma unroll
  for (int e = 0; e < 8; ++e) a[e] = 0.0f;
#pragma unroll
  for (int ks = 0; ks < KS1; ++ks) {
    float4 lo = *(const float4*)&p1[ks * S + base];
    float4 hi = *(const float4*)&p1[ks * S + base + 4];
    a[0] += lo.x; a[1] += lo.y; a[2] += lo.z; a[3] += lo.w;
    a[4] += hi.x; a[5] += hi.y; a[6] += hi.z; a[7] += hi.w;
  }
  const float s = 1.0f / 56.0f;
  const float G = a[7];
  __attribute__((aligned(16))) u16 o[8];
  float s7 = 0.0f;
#pragma unroll
  for (int k = 0; k < 7; ++k) {
    float v = (G - a[k]) * s;
    s7 += v;
    o[k] = f2bf(v);
  }
  o[7] = f2bf(s7);
  *(uint4*)&t7[base] = *(const uint4*)o;
}

// ---------------------------------------------------------------------------
// gemm2f (R9): fused NT GEMM, 128x64 tile, BK=64, NO split-K.
//   out[i][p] = s2 * ( sum_{j,k<7} t7[i][jk]*tap[j,k,p]  +  S7[i][j]*xb[j][p] )
// The xb term rides in the formerly-dead pad slots: A col j*8+7 = S7 (from
// reduce1), B row j*8+7 = raw xb.  B-gen is select-only u16 (no float math),
// tap offsets/masks hoisted out of the K-loop, and B-source loads are
// register-prefetched one iteration ahead (drained by the post-MFMA barrier).
// Writes scaled d_out directly.  grid = (2, 49, NB)
// ---------------------------------------------------------------------------
__global__ __launch_bounds__(256)
void gemm2f(const u16* __restrict__ A, const u16* __restrict__ xb,
            const u16* __restrict__ t1b, float* __restrict__ out) {
  __shared__ u16 As[128 * 64];
  __shared__ u16 Bs[64 * 64];

  const int nb = blockIdx.z;
  const u16* Ab  = A   + (long)nb * CC * CKP;
  const u16* xbn = xb  + (long)nb * CC * HW;
  const u16* t1n = t1b + (long)nb * CC * HW;
  const int m0 = blockIdx.x * 128, n0 = blockIdx.y * 64;
  const int t = threadIdx.x;
  const int lane = t & 63, wave = t >> 6;
  const int wm = wave & 1, wn = wave >> 1;        // 2(m) x 2(n of 32)
  const int lm = lane & 15, quad = lane >> 4;

  // B-gen mapping: pr = p-row, jg -> 2 channels per thread per iter
  const int pr = t & 63, jg = t >> 6;
  const int p  = n0 + pr;
  const int h  = p / WW, w = p - h * WW;
  const int h2 = (h + HH - 1) % HH;               // roll +1 on h
  const int w2 = (w + 1) % WW;                    // roll -1 on w
  const int swz = pr & 7;

  // hoisted per-k tap offsets + masks (iter-invariant, depend on p only)
  int toff[7], tmsk[7];
#pragma unroll
  for (int k = 0; k < 7; ++k) {
    int ww = w2 + k - 3;
    int wc = ww < 0 ? 0 : (ww > 55 ? 55 : ww);    // clamped, in-bounds
    toff[k] = h2 * WW + wc;
    tmsk[k] = ((unsigned)ww < 56u);
  }

  f32x4 acc[4][2];
#pragma unroll
  for (int a = 0; a < 4; ++a)
#pragma unroll
    for (int b = 0; b < 2; ++b) acc[a][b] = (f32x4)0.0f;

  int rowc[4], colc[4];
#pragma unroll
  for (int ci = 0; ci < 4; ++ci) {
    int c = t + ci * 256;
    rowc[ci] = c >> 3;
    colc[ci] = ((c & 7) ^ (rowc[ci] & 7)) * 8;
  }

  // B-source register prefetch (one iter ahead): 14 taps + 2 xb per thread
  u16 tr[2][7], xr[2];
#pragma unroll
  for (int jj = 0; jj < 2; ++jj) {                // prologue: it = 0
    const int jch = jg * 2 + jj;
    const int jmm = (jch + CC - 1) & (CC - 1);
    const u16* trow = t1n + (long)jmm * HW;
#pragma unroll
    for (int k = 0; k < 7; ++k) tr[jj][k] = trow[toff[k]];
    xr[jj] = xbn[(long)jch * HW + p];
  }

  for (int it = 0; it < 32; ++it) {
    const int k0 = it * 64;
#pragma unroll
    for (int ci = 0; ci < 4; ++ci)
      lds_load16(Ab + (long)(m0 + rowc[ci]) * CKP + k0 + colc[ci],
                 &As[(t + ci * 256) * 8]);

    // ---- B build from prefetched regs: pure u16 selects + one 16B store ----
#pragma unroll
    for (int jj = 0; jj < 2; ++jj) {
      __attribute__((aligned(16))) u16 v[8];
#pragma unroll
      for (int k = 0; k < 7; ++k) v[k] = tmsk[k] ? tr[jj][k] : (u16)0;
      v[7] = xr[jj];                              // pad slot carries xb term
      *(uint4*)&Bs[pr * 64 + (((jg * 2 + jj) ^ swz) * 8)] = *(const uint4*)v;
    }
    __syncthreads();

    // ---- prefetch B sources for it+1; lands during MFMA phase ----
    if (it < 31) {
#pragma unroll
      for (int jj = 0; jj < 2; ++jj) {
        const int jch = (it + 1) * 8 + jg * 2 + jj;
        const int jmm = (jch + CC - 1) & (CC - 1);
        const u16* trow = t1n + (long)jmm * HW;
#pragma unroll
        for (int k = 0; k < 7; ++k) tr[jj][k] = trow[toff[k]];
        xr[jj] = xbn[(long)jch * HW + p];
      }
    }

#pragma unroll
    for (int kk = 0; kk < 2; ++kk) {
      const int phys = ((kk * 4 + quad) ^ (lm & 7)) * 8;
      bf16x8 af[4], bv[2];
#pragma unroll
      for (int mi = 0; mi < 4; ++mi)
        af[mi] = *(const bf16x8*)&As[(wm * 64 + mi * 16 + lm) * 64 + phys];
#pragma unroll
      for (int ni = 0; ni < 2; ++ni)
        bv[ni] = *(const bf16x8*)&Bs[(wn * 32 + ni * 16 + lm) * 64 + phys];
#pragma unroll
      for (int mi = 0; mi < 4; ++mi)
#pragma unroll
        for (int ni = 0; ni < 2; ++ni)
          acc[mi][ni] = __builtin_amdgcn_mfma_f32_16x16x32_bf16(
              af[mi], bv[ni], acc[mi][ni], 0, 0, 0);
    }
    __syncthreads();
  }

  const float s2 = 0.023622783f;                  // 1/sqrt(1792)
  float* Ob = out + (long)nb * CC * HW;
#pragma unroll
  for (int mi = 0; mi < 4; ++mi)
#pragma unroll
    for (int ni = 0; ni < 2; ++ni) {
      int rb = m0 + wm * 64 + mi * 16 + quad * 4;
      int cg = n0 + wn * 32 + ni * 16 + lm;       // < 3136 always (49*64)
#pragma unroll
      for (int r = 0; r < 4; ++r)
        Ob[(long)(rb + r) * HW + cg] = acc[mi][ni][r] * s2;
    }
}

// ---------------------------------------------------------------------------
// Pipeline: pass1 -> gemm1f -> reduce1 -> gemm2f(-> d_out).  ~101 MB footprint.
// ---------------------------------------------------------------------------
extern "C" void kernel_launch(void* const* d_in, const int* in_sizes, int n_in,
                              void* d_out, int out_size, void* d_ws, size_t ws_size,
                              hipStream_t stream) {
  const float* x   = (const float*)d_in[0];   // (8,256,56,56)
  const float* p1w = (const float*)d_in[1];   // (1,256,56,56)

  char* ws = (char*)d_ws;
  size_t o = 0;
  u16* xb  = (u16*)(ws + o); o += (size_t)NB * CC * HW * 2;          //  12.8 MB
  u16* t1b = (u16*)(ws + o); o += (size_t)NB * CC * HW * 2;          //  12.8 MB
  u16* t7  = (u16*)(ws + o); o += (size_t)NB * CC * CKP * 2;         //   8.4 MB
  float* p1 = (float*)(ws + o); o += (size_t)KS1 * NB * CC * CKP * 4; // 67.1 MB

  pass1<<<NB * CC * HW / 4 / 256, 256, 0, stream>>>(x, p1w, t1b, xb);
  gemm1f<<<dim3(2, 16, NB * KS1), 256, 0, stream>>>(xb, t1b, p1);
  reduce1<<<NB * CC * CKP / 8 / 256, 256, 0, stream>>>(p1, t7);
  gemm2f<<<dim3(2, 49, NB), 256, 0, stream>>>(t7, xb, t1b, (float*)d_out);
}